// Round 1
// baseline (82722.455 us; speedup 1.0000x reference)
//
#include <hip/hip_runtime.h>
#include <math.h>

#define SQ 4096
#define HD 512
#define HHD 256
#define TS 8   // sequence rows per block in the parallel GEMMs

// ---------------- Kernel A: x = concat(inputs[0], note_emb[ids], chunk_emb[ids]) @ W_comb + b_comb
__global__ __launch_bounds__(512) void kA(const float* __restrict__ inputs,
                                          const int* __restrict__ nid,
                                          const int* __restrict__ cid,
                                          const float* __restrict__ note_emb,
                                          const float* __restrict__ chunk_emb,
                                          const float* __restrict__ Wc,
                                          const float* __restrict__ bc,
                                          float* __restrict__ xln) {
  __shared__ float xcat[TS][1536];
  const int t = threadIdx.x;          // 0..511
  const int s0 = blockIdx.x * TS;
  for (int si = 0; si < TS; ++si) {
    const int s = s0 + si;            // batch 0 only
    xcat[si][t]        = inputs[s * HD + t];
    xcat[si][512 + t]  = note_emb[nid[s] * HD + t];
    xcat[si][1024 + t] = chunk_emb[cid[s] * HD + t];
  }
  __syncthreads();
  float acc[TS];
  const float bcv = bc[t];
#pragma unroll
  for (int si = 0; si < TS; ++si) acc[si] = bcv;
  for (int r = 0; r < 1536; r += 4) {
    const float w0 = Wc[(r + 0) * HD + t];
    const float w1 = Wc[(r + 1) * HD + t];
    const float w2 = Wc[(r + 2) * HD + t];
    const float w3 = Wc[(r + 3) * HD + t];
#pragma unroll
    for (int si = 0; si < TS; ++si) {
      const float4 xv = *reinterpret_cast<const float4*>(&xcat[si][r]);
      acc[si] = fmaf(xv.x, w0, acc[si]);
      acc[si] = fmaf(xv.y, w1, acc[si]);
      acc[si] = fmaf(xv.z, w2, acc[si]);
      acc[si] = fmaf(xv.w, w3, acc[si]);
    }
  }
  for (int si = 0; si < TS; ++si) xln[(s0 + si) * HD + t] = acc[si];
}

// ---------------- Kernel B: in-place LayerNorm over H=512 per row
__global__ __launch_bounds__(256) void kB(float* __restrict__ xln,
                                          const float* __restrict__ g,
                                          const float* __restrict__ b) {
  __shared__ float red[4];
  __shared__ float mu_s, rs_s;
  const int s = blockIdx.x;
  const int t = threadIdx.x;          // 0..255
  const int wave = t >> 6, lane = t & 63;
  float v0 = xln[s * HD + t];
  float v1 = xln[s * HD + t + 256];
  float sum = v0 + v1;
#pragma unroll
  for (int o = 32; o >= 1; o >>= 1) sum += __shfl_down(sum, o, 64);
  if (lane == 0) red[wave] = sum;
  __syncthreads();
  if (t == 0) mu_s = (red[0] + red[1] + red[2] + red[3]) * (1.0f / 512.0f);
  __syncthreads();
  const float mu = mu_s;
  const float d0 = v0 - mu, d1 = v1 - mu;
  float vs = d0 * d0 + d1 * d1;
#pragma unroll
  for (int o = 32; o >= 1; o >>= 1) vs += __shfl_down(vs, o, 64);
  if (lane == 0) red[wave] = vs;
  __syncthreads();
  if (t == 0) rs_s = rsqrtf((red[0] + red[1] + red[2] + red[3]) * (1.0f / 512.0f) + 1e-12f);
  __syncthreads();
  const float rs = rs_s;
  xln[s * HD + t]       = d0 * rs * g[t] + b[t];
  xln[s * HD + t + 256] = d1 * rs * g[t + 256] + b[t + 256];
}

// ---------------- Kernel C: gx[dir][s][k*256+j] = x[s_eff] @ Wx[dir][k][:,j] + bg[dir][k][j]
__global__ __launch_bounds__(512) void kC(const float* __restrict__ xln,
                                          const float* __restrict__ Wx,
                                          const float* __restrict__ bg,
                                          float* __restrict__ gx) {
  __shared__ float xs[TS][HD];
  const int t = threadIdx.x;          // 0..511
  const int dir = blockIdx.y;
  const int s0 = blockIdx.x * TS;
  for (int si = 0; si < TS; ++si) {
    const int sx = dir ? (SQ - 1 - (s0 + si)) : (s0 + si);
    xs[si][t] = xln[sx * HD + t];
  }
  __syncthreads();
  // two output columns per thread: c1 = t (k1=t>>8), c2 = t+512 (k2=2+(t>>8))
  const int k1 = t >> 8, j = t & 255;
  const int k2 = k1 + 2;
  const float* w1 = Wx + (size_t)(dir * 4 + k1) * HD * HHD + j;
  const float* w2 = Wx + (size_t)(dir * 4 + k2) * HD * HHD + j;
  float acc1[TS], acc2[TS];
  const float b1 = bg[(dir * 4 + k1) * HHD + j];
  const float b2 = bg[(dir * 4 + k2) * HHD + j];
#pragma unroll
  for (int si = 0; si < TS; ++si) { acc1[si] = b1; acc2[si] = b2; }
  for (int d = 0; d < HD; d += 4) {
    const float w1a = w1[(d + 0) * HHD], w1b = w1[(d + 1) * HHD];
    const float w1c = w1[(d + 2) * HHD], w1d = w1[(d + 3) * HHD];
    const float w2a = w2[(d + 0) * HHD], w2b = w2[(d + 1) * HHD];
    const float w2c = w2[(d + 2) * HHD], w2d = w2[(d + 3) * HHD];
#pragma unroll
    for (int si = 0; si < TS; ++si) {
      const float4 xv = *reinterpret_cast<const float4*>(&xs[si][d]);
      acc1[si] = fmaf(xv.x, w1a, acc1[si]);
      acc1[si] = fmaf(xv.y, w1b, acc1[si]);
      acc1[si] = fmaf(xv.z, w1c, acc1[si]);
      acc1[si] = fmaf(xv.w, w1d, acc1[si]);
      acc2[si] = fmaf(xv.x, w2a, acc2[si]);
      acc2[si] = fmaf(xv.y, w2b, acc2[si]);
      acc2[si] = fmaf(xv.z, w2c, acc2[si]);
      acc2[si] = fmaf(xv.w, w2d, acc2[si]);
    }
  }
  for (int si = 0; si < TS; ++si) {
    float* row = gx + ((size_t)(dir * SQ + s0 + si)) * 1024;
    row[t]       = acc1[si];
    row[t + 512] = acc2[si];
  }
}

// ---------------- Kernel R: the sequential TLSTM recurrence (one block per direction)
__global__ __launch_bounds__(1024, 4) void kR(const float* __restrict__ gx,
                                              const float* __restrict__ Wh,
                                              const float* __restrict__ Wd,
                                              const float* __restrict__ bd,
                                              const float* __restrict__ times,
                                              float* __restrict__ hfin) {
  const int dir = blockIdx.x;
  const int t = threadIdx.x;          // 0..1023
  const int k = t >> 8, j = t & 255;
  __shared__ float h_lds[HHD];
  __shared__ float c_lds[HHD];
  __shared__ float g_lds[4][HHD];
  __shared__ float wdp_lds[4][HHD];

  // persistent weights in registers: Wh column j of gate k (256), Wd rows [64k,64k+64) col j (64)
  float wh[256];
  const float* whp = Wh + ((size_t)(dir * 4 + k) * HHD) * HHD + j;
#pragma unroll
  for (int i = 0; i < 256; ++i) wh[i] = whp[i * HHD];
  float wd[64];
  const float* wdpp = Wd + (size_t)dir * HHD * HHD + (k * 64) * HHD + j;
#pragma unroll
  for (int i = 0; i < 64; ++i) wd[i] = wdpp[i * HHD];
  const float bdv = (t < 256) ? bd[dir * HHD + t] : 0.0f;

  if (t < 256) { h_lds[t] = 0.0f; c_lds[t] = 0.0f; }
  __syncthreads();

  const float* gxd = gx + (size_t)dir * SQ * 1024;
  for (int s = 0; s < SQ; ++s) {
    const float gxv = gxd[s * 1024 + t];   // input-side gate preactivation (global, L2-hot)
    // gate dot: h @ Wh[:,col]
    float acc = 0.0f;
    const float4* h4 = reinterpret_cast<const float4*>(h_lds);
#pragma unroll
    for (int ii = 0; ii < 64; ++ii) {
      const float4 hv = h4[ii];
      acc = fmaf(wh[4 * ii + 0], hv.x, acc);
      acc = fmaf(wh[4 * ii + 1], hv.y, acc);
      acc = fmaf(wh[4 * ii + 2], hv.z, acc);
      acc = fmaf(wh[4 * ii + 3], hv.w, acc);
    }
    // Wd partial: quarter K-slice of c @ Wd[:,j]
    float wacc = 0.0f;
    const float4* c4 = reinterpret_cast<const float4*>(c_lds) + k * 16;
#pragma unroll
    for (int ii = 0; ii < 16; ++ii) {
      const float4 cv = c4[ii];
      wacc = fmaf(wd[4 * ii + 0], cv.x, wacc);
      wacc = fmaf(wd[4 * ii + 1], cv.y, wacc);
      wacc = fmaf(wd[4 * ii + 2], cv.z, wacc);
      wacc = fmaf(wd[4 * ii + 3], cv.w, wacc);
    }
    const float pre = acc + gxv;
    g_lds[k][j]   = 1.0f / (1.0f + __expf(-pre));
    wdp_lds[k][j] = wacc;
    __syncthreads();
    if (t < 256) {
      const float wsum = wdp_lds[0][t] + wdp_lds[1][t] + wdp_lds[2][t] + wdp_lds[3][t];
      const float c_st = tanhf(wsum + bdv);
      const int sidx = dir ? ((s == 0) ? 0 : (SQ - s)) : s;
      const float tv = times[sidx];       // batch 0 row of (B,S,1)
      const float T = 1.0f / logf(tv + 2.7182818284590452354f);
      const float cold = c_lds[t];
      const float c_adj = cold + (T - 1.0f) * c_st;
      const float iv = g_lds[0][t], fv = g_lds[1][t], ov = g_lds[2][t], cgv = g_lds[3][t];
      const float ct = fv * c_adj + iv * cgv;
      const float hn = ov * tanhf(ct);
      c_lds[t] = ct;
      h_lds[t] = hn;
    }
    __syncthreads();
  }
  if (t < 256) hfin[dir * HHD + t] = h_lds[t];
}

// ---------------- Kernel D: logits = concat(hf,hb) @ W_cls + b_cls -> sigmoid -> out
__global__ __launch_bounds__(512) void kD(const float* __restrict__ hfin,
                                          const float* __restrict__ Wcls,
                                          const float* __restrict__ bcls,
                                          float* __restrict__ out) {
  __shared__ float red[8];
  const int t = threadIdx.x;          // 0..511
  float v = hfin[t] * Wcls[t];
#pragma unroll
  for (int o = 32; o >= 1; o >>= 1) v += __shfl_down(v, o, 64);
  if ((t & 63) == 0) red[t >> 6] = v;
  __syncthreads();
  if (t == 0) {
    float l = red[0] + red[1] + red[2] + red[3] + red[4] + red[5] + red[6] + red[7] + bcls[0];
    if (isnan(l) || isinf(l)) l = 0.0f;
    float p = 1.0f / (1.0f + expf(-l));
    if (isnan(p) || isinf(p)) p = 0.0f;
    out[0] = p;
  }
}

extern "C" void kernel_launch(void* const* d_in, const int* in_sizes, int n_in,
                              void* d_out, int out_size, void* d_ws, size_t ws_size,
                              hipStream_t stream) {
  const float* inputs    = (const float*)d_in[0];
  const float* times     = (const float*)d_in[1];
  const int*   nid       = (const int*)d_in[2];
  const int*   cid       = (const int*)d_in[3];
  const float* note_emb  = (const float*)d_in[4];
  const float* chunk_emb = (const float*)d_in[5];
  const float* W_comb    = (const float*)d_in[6];
  const float* b_comb    = (const float*)d_in[7];
  const float* ln_g      = (const float*)d_in[8];
  const float* ln_b      = (const float*)d_in[9];
  const float* Wx        = (const float*)d_in[10];
  const float* Wh        = (const float*)d_in[11];
  const float* bg        = (const float*)d_in[12];
  const float* Wd        = (const float*)d_in[13];
  const float* bd        = (const float*)d_in[14];
  const float* W_cls     = (const float*)d_in[15];
  const float* b_cls     = (const float*)d_in[16];

  float* ws   = (float*)d_ws;
  float* xln  = ws;                              // 4096*512   = 2,097,152 floats
  float* gx   = ws + (size_t)SQ * HD;            // 2*4096*1024= 8,388,608 floats
  float* hfin = gx + (size_t)2 * SQ * 1024;      // 512 floats

  kA<<<SQ / TS, 512, 0, stream>>>(inputs, nid, cid, note_emb, chunk_emb, W_comb, b_comb, xln);
  kB<<<SQ, 256, 0, stream>>>(xln, ln_g, ln_b);
  kC<<<dim3(SQ / TS, 2), 512, 0, stream>>>(xln, Wx, bg, gx);
  kR<<<2, 1024, 0, stream>>>(gx, Wh, Wd, bd, times, hfin);
  kD<<<1, 512, 0, stream>>>(hfin, W_cls, b_cls, (float*)d_out);
}

// Round 2
// 21475.267 us; speedup vs baseline: 3.8520x; 3.8520x over previous
//
#include <hip/hip_runtime.h>
#include <math.h>

#define SQ 4096
#define HD 512
#define HHD 256
#define TS 8   // sequence rows per block in the parallel GEMMs

// ---------------- Kernel A: x = concat(inputs[0], note_emb[ids], chunk_emb[ids]) @ W_comb + b_comb
__global__ __launch_bounds__(512) void kA(const float* __restrict__ inputs,
                                          const int* __restrict__ nid,
                                          const int* __restrict__ cid,
                                          const float* __restrict__ note_emb,
                                          const float* __restrict__ chunk_emb,
                                          const float* __restrict__ Wc,
                                          const float* __restrict__ bc,
                                          float* __restrict__ xln) {
  __shared__ float xcat[TS][1536];
  const int t = threadIdx.x;          // 0..511
  const int s0 = blockIdx.x * TS;
  for (int si = 0; si < TS; ++si) {
    const int s = s0 + si;            // batch 0 only
    xcat[si][t]        = inputs[s * HD + t];
    xcat[si][512 + t]  = note_emb[nid[s] * HD + t];
    xcat[si][1024 + t] = chunk_emb[cid[s] * HD + t];
  }
  __syncthreads();
  float acc[TS];
  const float bcv = bc[t];
#pragma unroll
  for (int si = 0; si < TS; ++si) acc[si] = bcv;
  for (int r = 0; r < 1536; r += 4) {
    const float w0 = Wc[(r + 0) * HD + t];
    const float w1 = Wc[(r + 1) * HD + t];
    const float w2 = Wc[(r + 2) * HD + t];
    const float w3 = Wc[(r + 3) * HD + t];
#pragma unroll
    for (int si = 0; si < TS; ++si) {
      const float4 xv = *reinterpret_cast<const float4*>(&xcat[si][r]);
      acc[si] = fmaf(xv.x, w0, acc[si]);
      acc[si] = fmaf(xv.y, w1, acc[si]);
      acc[si] = fmaf(xv.z, w2, acc[si]);
      acc[si] = fmaf(xv.w, w3, acc[si]);
    }
  }
  for (int si = 0; si < TS; ++si) xln[(s0 + si) * HD + t] = acc[si];
}

// ---------------- Kernel B: in-place LayerNorm over H=512 per row
__global__ __launch_bounds__(256) void kB(float* __restrict__ xln,
                                          const float* __restrict__ g,
                                          const float* __restrict__ b) {
  __shared__ float red[4];
  __shared__ float mu_s, rs_s;
  const int s = blockIdx.x;
  const int t = threadIdx.x;          // 0..255
  const int wave = t >> 6, lane = t & 63;
  float v0 = xln[s * HD + t];
  float v1 = xln[s * HD + t + 256];
  float sum = v0 + v1;
#pragma unroll
  for (int o = 32; o >= 1; o >>= 1) sum += __shfl_down(sum, o, 64);
  if (lane == 0) red[wave] = sum;
  __syncthreads();
  if (t == 0) mu_s = (red[0] + red[1] + red[2] + red[3]) * (1.0f / 512.0f);
  __syncthreads();
  const float mu = mu_s;
  const float d0 = v0 - mu, d1 = v1 - mu;
  float vs = d0 * d0 + d1 * d1;
#pragma unroll
  for (int o = 32; o >= 1; o >>= 1) vs += __shfl_down(vs, o, 64);
  if (lane == 0) red[wave] = vs;
  __syncthreads();
  if (t == 0) rs_s = rsqrtf((red[0] + red[1] + red[2] + red[3]) * (1.0f / 512.0f) + 1e-12f);
  __syncthreads();
  const float rs = rs_s;
  xln[s * HD + t]       = d0 * rs * g[t] + b[t];
  xln[s * HD + t + 256] = d1 * rs * g[t + 256] + b[t + 256];
}

// ---------------- Kernel C: gx[dir][s][k*256+j] = x[s_eff] @ Wx[dir][k][:,j] + bg[dir][k][j]
__global__ __launch_bounds__(512) void kC(const float* __restrict__ xln,
                                          const float* __restrict__ Wx,
                                          const float* __restrict__ bg,
                                          float* __restrict__ gx) {
  __shared__ float xs[TS][HD];
  const int t = threadIdx.x;          // 0..511
  const int dir = blockIdx.y;
  const int s0 = blockIdx.x * TS;
  for (int si = 0; si < TS; ++si) {
    const int sx = dir ? (SQ - 1 - (s0 + si)) : (s0 + si);
    xs[si][t] = xln[sx * HD + t];
  }
  __syncthreads();
  const int k1 = t >> 8, j = t & 255;
  const int k2 = k1 + 2;
  const float* w1 = Wx + (size_t)(dir * 4 + k1) * HD * HHD + j;
  const float* w2 = Wx + (size_t)(dir * 4 + k2) * HD * HHD + j;
  float acc1[TS], acc2[TS];
  const float b1 = bg[(dir * 4 + k1) * HHD + j];
  const float b2 = bg[(dir * 4 + k2) * HHD + j];
#pragma unroll
  for (int si = 0; si < TS; ++si) { acc1[si] = b1; acc2[si] = b2; }
  for (int d = 0; d < HD; d += 4) {
    const float w1a = w1[(d + 0) * HHD], w1b = w1[(d + 1) * HHD];
    const float w1c = w1[(d + 2) * HHD], w1d = w1[(d + 3) * HHD];
    const float w2a = w2[(d + 0) * HHD], w2b = w2[(d + 1) * HHD];
    const float w2c = w2[(d + 2) * HHD], w2d = w2[(d + 3) * HHD];
#pragma unroll
    for (int si = 0; si < TS; ++si) {
      const float4 xv = *reinterpret_cast<const float4*>(&xs[si][d]);
      acc1[si] = fmaf(xv.x, w1a, acc1[si]);
      acc1[si] = fmaf(xv.y, w1b, acc1[si]);
      acc1[si] = fmaf(xv.z, w1c, acc1[si]);
      acc1[si] = fmaf(xv.w, w1d, acc1[si]);
      acc2[si] = fmaf(xv.x, w2a, acc2[si]);
      acc2[si] = fmaf(xv.y, w2b, acc2[si]);
      acc2[si] = fmaf(xv.z, w2c, acc2[si]);
      acc2[si] = fmaf(xv.w, w2d, acc2[si]);
    }
  }
  for (int si = 0; si < TS; ++si) {
    float* row = gx + ((size_t)(dir * SQ + s0 + si)) * 1024;
    row[t]       = acc1[si];
    row[t + 512] = acc2[si];
  }
}

// ---------------- Kernel R: sequential TLSTM recurrence.
// 8 workgroups: dir = blockIdx.x>>2, wg = blockIdx.x&3. Each WG owns 64 hidden
// columns; weights live in VGPRs (256 Wh + 64 Wd per thread; 256 thr = 1 wave/SIMD
// -> 512-VGPR cap, no spill). Cross-WG h/c exchange each step via global chunks +
// monotone flags (d_ws poison 0xAA is negative as int, so no flag init needed;
// double-buffered data; publish strictly precedes poll in program order).
__global__ __launch_bounds__(256, 1) void kR(const float* __restrict__ gx,
                                             const float* __restrict__ Wh,
                                             const float* __restrict__ Wd,
                                             const float* __restrict__ bd,
                                             const float* __restrict__ times,
                                             float* __restrict__ comm,
                                             float* __restrict__ hfin) {
  const int dir = blockIdx.x >> 2;
  const int wg  = blockIdx.x & 3;
  const int t   = threadIdx.x;        // 0..255
  const int k   = t >> 6;             // gate 0..3
  const int u   = t & 63;             // local column
  const int c0  = wg * 64;
  const int j   = c0 + u;             // global column 0..255

  int*   flags = (int*)comm;                       // (dir*4+wg)*32, padded to 128B
  float* bufs  = comm + 256;                       // chunks: ((dir*4+wg)*2+buf)*128

  // Persistent weights in registers.
  float wh[256];
  const float* whp = Wh + ((size_t)(dir * 4 + k) * HHD) * HHD + j;
#pragma unroll
  for (int i = 0; i < 256; ++i) wh[i] = whp[i * HHD];
  float wd[64];
  const float* wdpp = Wd + (size_t)dir * HHD * HHD + (k * 64) * HHD + j;
#pragma unroll
  for (int i = 0; i < 64; ++i) wd[i] = wdpp[i * HHD];

  __shared__ float h_all[HHD];
  __shared__ float c_all[HHD];
  __shared__ float g_lds[4][64];
  __shared__ float wdp_lds[4][64];

  h_all[t] = 0.0f;
  c_all[t] = 0.0f;
  __syncthreads();

  int* myflag = flags + (dir * 4 + wg) * 32;
  const float* gxd = gx + (size_t)dir * SQ * 1024;
  const float bdv = (t < 64) ? bd[dir * HHD + c0 + t] : 0.0f;

  for (int s = 0; s < SQ; ++s) {
    const float gxv = gxd[(size_t)s * 1024 + k * 256 + j];
    float tv = 0.0f;
    if (t < 64) {
      const int sidx = dir ? ((s == 0) ? 0 : (SQ - s)) : s;
      tv = times[sidx];
    }
    // gate preactivation: h_all @ Wh[:, j]
    float acc = 0.0f;
    const float4* h4 = reinterpret_cast<const float4*>(h_all);
#pragma unroll
    for (int ii = 0; ii < 64; ++ii) {
      const float4 hv = h4[ii];
      acc = fmaf(wh[4 * ii + 0], hv.x, acc);
      acc = fmaf(wh[4 * ii + 1], hv.y, acc);
      acc = fmaf(wh[4 * ii + 2], hv.z, acc);
      acc = fmaf(wh[4 * ii + 3], hv.w, acc);
    }
    // partial of c_all @ Wd[:, j]: rows [64k, 64k+64)
    float wacc = 0.0f;
    const float4* c4 = reinterpret_cast<const float4*>(c_all) + k * 16;
#pragma unroll
    for (int ii = 0; ii < 16; ++ii) {
      const float4 cv = c4[ii];
      wacc = fmaf(wd[4 * ii + 0], cv.x, wacc);
      wacc = fmaf(wd[4 * ii + 1], cv.y, wacc);
      wacc = fmaf(wd[4 * ii + 2], cv.z, wacc);
      wacc = fmaf(wd[4 * ii + 3], cv.w, wacc);
    }
    g_lds[k][u]   = 1.0f / (1.0f + __expf(-(acc + gxv)));
    wdp_lds[k][u] = wacc;
    __syncthreads();
    if (t < 64) {
      const float wsum = wdp_lds[0][t] + wdp_lds[1][t] + wdp_lds[2][t] + wdp_lds[3][t];
      const float c_st = tanhf(wsum + bdv);
      const float T = 1.0f / logf(tv + 2.7182818284590452354f);
      const int jj = c0 + t;
      const float c_adj = c_all[jj] + (T - 1.0f) * c_st;
      const float iv = g_lds[0][t], fv = g_lds[1][t], ov = g_lds[2][t], cgv = g_lds[3][t];
      const float ct = fv * c_adj + iv * cgv;
      const float hn = ov * tanhf(ct);
      c_all[jj] = ct;
      h_all[jj] = hn;
      float* chunk = bufs + (size_t)(((dir * 4 + wg) * 2) + (s & 1)) * 128;
      __hip_atomic_store(chunk + t,      hn, __ATOMIC_RELAXED, __HIP_MEMORY_SCOPE_AGENT);
      __hip_atomic_store(chunk + 64 + t, ct, __ATOMIC_RELAXED, __HIP_MEMORY_SCOPE_AGENT);
    }
    __syncthreads();   // chunk stores drained (barrier implies vmcnt(0))
    if (t == 0) {
      __threadfence();
      __hip_atomic_store(myflag, s + 1, __ATOMIC_RELEASE, __HIP_MEMORY_SCOPE_AGENT);
    }
    if (t >= 1 && t <= 3) {           // publish strictly precedes poll in program order
      int* f = flags + (dir * 4 + ((wg + t) & 3)) * 32;
      while (__hip_atomic_load(f, __ATOMIC_ACQUIRE, __HIP_MEMORY_SCOPE_AGENT) < s + 1) {
        __builtin_amdgcn_s_sleep(1);
      }
    }
    __syncthreads();
    if (t < 192) {
      const int m = t >> 6, uu = t & 63;
      const int sib = (wg + 1 + m) & 3;
      const float* chunk = bufs + (size_t)(((dir * 4 + sib) * 2) + (s & 1)) * 128;
      h_all[sib * 64 + uu] = __hip_atomic_load(chunk + uu,      __ATOMIC_RELAXED, __HIP_MEMORY_SCOPE_AGENT);
      c_all[sib * 64 + uu] = __hip_atomic_load(chunk + 64 + uu, __ATOMIC_RELAXED, __HIP_MEMORY_SCOPE_AGENT);
    }
    __syncthreads();
  }
  if (t < 64) hfin[dir * HHD + c0 + t] = h_all[c0 + t];
}

// ---------------- Kernel D: logits = concat(hf,hb) @ W_cls + b_cls -> sigmoid -> out
__global__ __launch_bounds__(512) void kD(const float* __restrict__ hfin,
                                          const float* __restrict__ Wcls,
                                          const float* __restrict__ bcls,
                                          float* __restrict__ out) {
  __shared__ float red[8];
  const int t = threadIdx.x;          // 0..511
  float v = hfin[t] * Wcls[t];
#pragma unroll
  for (int o = 32; o >= 1; o >>= 1) v += __shfl_down(v, o, 64);
  if ((t & 63) == 0) red[t >> 6] = v;
  __syncthreads();
  if (t == 0) {
    float l = red[0] + red[1] + red[2] + red[3] + red[4] + red[5] + red[6] + red[7] + bcls[0];
    if (isnan(l) || isinf(l)) l = 0.0f;
    float p = 1.0f / (1.0f + expf(-l));
    if (isnan(p) || isinf(p)) p = 0.0f;
    out[0] = p;
  }
}

extern "C" void kernel_launch(void* const* d_in, const int* in_sizes, int n_in,
                              void* d_out, int out_size, void* d_ws, size_t ws_size,
                              hipStream_t stream) {
  const float* inputs    = (const float*)d_in[0];
  const float* times     = (const float*)d_in[1];
  const int*   nid       = (const int*)d_in[2];
  const int*   cid       = (const int*)d_in[3];
  const float* note_emb  = (const float*)d_in[4];
  const float* chunk_emb = (const float*)d_in[5];
  const float* W_comb    = (const float*)d_in[6];
  const float* b_comb    = (const float*)d_in[7];
  const float* ln_g      = (const float*)d_in[8];
  const float* ln_b      = (const float*)d_in[9];
  const float* Wx        = (const float*)d_in[10];
  const float* Wh        = (const float*)d_in[11];
  const float* bg        = (const float*)d_in[12];
  const float* Wd        = (const float*)d_in[13];
  const float* bd        = (const float*)d_in[14];
  const float* W_cls     = (const float*)d_in[15];
  const float* b_cls     = (const float*)d_in[16];

  float* ws   = (float*)d_ws;
  float* xln  = ws;                              // 4096*512    floats
  float* gx   = ws + (size_t)SQ * HD;            // 2*4096*1024 floats
  float* hfin = gx + (size_t)2 * SQ * 1024;      // 512 floats
  float* comm = hfin + 512;                      // flags (8*32 ints) + chunks (8*2*128 floats)

  kA<<<SQ / TS, 512, 0, stream>>>(inputs, nid, cid, note_emb, chunk_emb, W_comb, b_comb, xln);
  kB<<<SQ, 256, 0, stream>>>(xln, ln_g, ln_b);
  kC<<<dim3(SQ / TS, 2), 512, 0, stream>>>(xln, Wx, bg, gx);
  kR<<<8, 256, 0, stream>>>(gx, Wh, Wd, bd, times, comm, hfin);
  kD<<<1, 512, 0, stream>>>(hfin, W_cls, b_cls, (float*)d_out);
}

// Round 3
// 19578.046 us; speedup vs baseline: 4.2253x; 1.0969x over previous
//
#include <hip/hip_runtime.h>
#include <math.h>

#define SQ 4096
#define HD 512
#define HHD 256
#define TS 8   // sequence rows per block in the parallel GEMMs

// ---------------- Kernel A: x = concat(inputs[0], note_emb[ids], chunk_emb[ids]) @ W_comb + b_comb
__global__ __launch_bounds__(512) void kA(const float* __restrict__ inputs,
                                          const int* __restrict__ nid,
                                          const int* __restrict__ cid,
                                          const float* __restrict__ note_emb,
                                          const float* __restrict__ chunk_emb,
                                          const float* __restrict__ Wc,
                                          const float* __restrict__ bc,
                                          float* __restrict__ xln) {
  __shared__ float xcat[TS][1536];
  const int t = threadIdx.x;          // 0..511
  const int s0 = blockIdx.x * TS;
  for (int si = 0; si < TS; ++si) {
    const int s = s0 + si;            // batch 0 only
    xcat[si][t]        = inputs[s * HD + t];
    xcat[si][512 + t]  = note_emb[nid[s] * HD + t];
    xcat[si][1024 + t] = chunk_emb[cid[s] * HD + t];
  }
  __syncthreads();
  float acc[TS];
  const float bcv = bc[t];
#pragma unroll
  for (int si = 0; si < TS; ++si) acc[si] = bcv;
  for (int r = 0; r < 1536; r += 4) {
    const float w0 = Wc[(r + 0) * HD + t];
    const float w1 = Wc[(r + 1) * HD + t];
    const float w2 = Wc[(r + 2) * HD + t];
    const float w3 = Wc[(r + 3) * HD + t];
#pragma unroll
    for (int si = 0; si < TS; ++si) {
      const float4 xv = *reinterpret_cast<const float4*>(&xcat[si][r]);
      acc[si] = fmaf(xv.x, w0, acc[si]);
      acc[si] = fmaf(xv.y, w1, acc[si]);
      acc[si] = fmaf(xv.z, w2, acc[si]);
      acc[si] = fmaf(xv.w, w3, acc[si]);
    }
  }
  for (int si = 0; si < TS; ++si) xln[(s0 + si) * HD + t] = acc[si];
}

// ---------------- Kernel B: in-place LayerNorm over H=512 per row
__global__ __launch_bounds__(256) void kB(float* __restrict__ xln,
                                          const float* __restrict__ g,
                                          const float* __restrict__ b) {
  __shared__ float red[4];
  __shared__ float mu_s, rs_s;
  const int s = blockIdx.x;
  const int t = threadIdx.x;          // 0..255
  const int wave = t >> 6, lane = t & 63;
  float v0 = xln[s * HD + t];
  float v1 = xln[s * HD + t + 256];
  float sum = v0 + v1;
#pragma unroll
  for (int o = 32; o >= 1; o >>= 1) sum += __shfl_down(sum, o, 64);
  if (lane == 0) red[wave] = sum;
  __syncthreads();
  if (t == 0) mu_s = (red[0] + red[1] + red[2] + red[3]) * (1.0f / 512.0f);
  __syncthreads();
  const float mu = mu_s;
  const float d0 = v0 - mu, d1 = v1 - mu;
  float vs = d0 * d0 + d1 * d1;
#pragma unroll
  for (int o = 32; o >= 1; o >>= 1) vs += __shfl_down(vs, o, 64);
  if (lane == 0) red[wave] = vs;
  __syncthreads();
  if (t == 0) rs_s = rsqrtf((red[0] + red[1] + red[2] + red[3]) * (1.0f / 512.0f) + 1e-12f);
  __syncthreads();
  const float rs = rs_s;
  xln[s * HD + t]       = d0 * rs * g[t] + b[t];
  xln[s * HD + t + 256] = d1 * rs * g[t + 256] + b[t + 256];
}

// ---------------- Kernel C: gx[dir][s][k*256+j] = x[s_eff] @ Wx[dir][k][:,j] + bg[dir][k][j]
__global__ __launch_bounds__(512) void kC(const float* __restrict__ xln,
                                          const float* __restrict__ Wx,
                                          const float* __restrict__ bg,
                                          float* __restrict__ gx) {
  __shared__ float xs[TS][HD];
  const int t = threadIdx.x;          // 0..511
  const int dir = blockIdx.y;
  const int s0 = blockIdx.x * TS;
  for (int si = 0; si < TS; ++si) {
    const int sx = dir ? (SQ - 1 - (s0 + si)) : (s0 + si);
    xs[si][t] = xln[sx * HD + t];
  }
  __syncthreads();
  const int k1 = t >> 8, j = t & 255;
  const int k2 = k1 + 2;
  const float* w1 = Wx + (size_t)(dir * 4 + k1) * HD * HHD + j;
  const float* w2 = Wx + (size_t)(dir * 4 + k2) * HD * HHD + j;
  float acc1[TS], acc2[TS];
  const float b1 = bg[(dir * 4 + k1) * HHD + j];
  const float b2 = bg[(dir * 4 + k2) * HHD + j];
#pragma unroll
  for (int si = 0; si < TS; ++si) { acc1[si] = b1; acc2[si] = b2; }
  for (int d = 0; d < HD; d += 4) {
    const float w1a = w1[(d + 0) * HHD], w1b = w1[(d + 1) * HHD];
    const float w1c = w1[(d + 2) * HHD], w1d = w1[(d + 3) * HHD];
    const float w2a = w2[(d + 0) * HHD], w2b = w2[(d + 1) * HHD];
    const float w2c = w2[(d + 2) * HHD], w2d = w2[(d + 3) * HHD];
#pragma unroll
    for (int si = 0; si < TS; ++si) {
      const float4 xv = *reinterpret_cast<const float4*>(&xs[si][d]);
      acc1[si] = fmaf(xv.x, w1a, acc1[si]);
      acc1[si] = fmaf(xv.y, w1b, acc1[si]);
      acc1[si] = fmaf(xv.z, w1c, acc1[si]);
      acc1[si] = fmaf(xv.w, w1d, acc1[si]);
      acc2[si] = fmaf(xv.x, w2a, acc2[si]);
      acc2[si] = fmaf(xv.y, w2b, acc2[si]);
      acc2[si] = fmaf(xv.z, w2c, acc2[si]);
      acc2[si] = fmaf(xv.w, w2d, acc2[si]);
    }
  }
  for (int si = 0; si < TS; ++si) {
    float* row = gx + ((size_t)(dir * SQ + s0 + si)) * 1024;
    row[t]       = acc1[si];
    row[t + 512] = acc2[si];
  }
}

// ---------------- Kernel R: sequential TLSTM recurrence.
// 8 WGs: dir = blockIdx.x>>2, wg = blockIdx.x&3. Each WG owns 64 hidden columns.
// Wave k (= gate k) holds Wh column slice in regs. Cross-WG h/c exchange via
// RELAXED agent-scope atomics only (per-access coherent, NO buffer_inv/wbl2 —
// round-2's acquire/release+threadfence cost ~4 us/step in cache maintenance).
// Producer ordering: chunk stores + flag store are same-wave; s_waitcnt vmcnt(0)
// between them. 2 barriers/step. Flags monotone; ws poison 0xAA is negative.
__global__ __launch_bounds__(256, 1) void kR(const float* __restrict__ gx,
                                             const float* __restrict__ Wh,
                                             const float* __restrict__ Wd,
                                             const float* __restrict__ bd,
                                             const float* __restrict__ times,
                                             float* __restrict__ comm,
                                             float* __restrict__ hfin) {
  const int dir = blockIdx.x >> 2;
  const int wg  = blockIdx.x & 3;
  const int t   = threadIdx.x;        // 0..255
  const int k   = t >> 6;             // gate index == wave id
  const int u   = t & 63;
  const int c0  = wg * 64;
  const int j   = c0 + u;             // owned global column

  int*   flags = (int*)comm;                       // 8 flags, stride 32 ints (128 B)
  float* bufs  = comm + 256;                       // chunks: ((dir*4+w)*2+buf)*128 floats

  // Persistent weights in registers (176 arch VGPR + AGPR overflow; 1 wave/SIMD).
  float wh[256];
  const float* whp = Wh + ((size_t)(dir * 4 + k) * HHD) * HHD + j;
#pragma unroll
  for (int i = 0; i < 256; ++i) wh[i] = whp[i * HHD];
  float wd[64];
  const float* wdpp = Wd + (size_t)dir * HHD * HHD + (k * 64) * HHD + j;
#pragma unroll
  for (int i = 0; i < 64; ++i) wd[i] = wdpp[i * HHD];

  __shared__ float h_all[HHD];
  __shared__ float c_all[HHD];
  __shared__ float g_lds[4][64];
  __shared__ float wdp_lds[4][64];
  __shared__ float T_pre[SQ];          // 16 KB: precomputed 1/log(t+e)

  for (int s = t; s < SQ; s += 256) {
    const int sidx = dir ? ((s == 0) ? 0 : (SQ - s)) : s;
    T_pre[s] = 1.0f / logf(times[sidx] + 2.7182818284590452354f);
  }
  h_all[t] = 0.0f;
  c_all[t] = 0.0f;
  __syncthreads();

  const float bdv = (k == 0) ? bd[dir * HHD + c0 + u] : 0.0f;
  int* myflag  = flags + (dir * 4 + wg) * 32;
  int* sibflag = flags + (dir * 4 + ((wg + k) & 3)) * 32;   // waves 1..3
  const int sib = (wg + k) & 3;
  const float* gxcol = gx + (size_t)dir * SQ * 1024 + (size_t)(k * 256 + j);

  for (int s = 0; s < SQ; ++s) {
    const float gxv = gxcol[(size_t)s * 1024];   // issued early; used after the dot
    // gate preactivation: h_all @ Wh[:, j]
    float acc = 0.0f;
    const float4* h4 = reinterpret_cast<const float4*>(h_all);
#pragma unroll
    for (int ii = 0; ii < 64; ++ii) {
      const float4 hv = h4[ii];
      acc = fmaf(wh[4 * ii + 0], hv.x, acc);
      acc = fmaf(wh[4 * ii + 1], hv.y, acc);
      acc = fmaf(wh[4 * ii + 2], hv.z, acc);
      acc = fmaf(wh[4 * ii + 3], hv.w, acc);
    }
    // partial of c_all @ Wd[:, j]: rows [64k, 64k+64)
    float wacc = 0.0f;
    const float4* c4 = reinterpret_cast<const float4*>(c_all) + k * 16;
#pragma unroll
    for (int ii = 0; ii < 16; ++ii) {
      const float4 cv = c4[ii];
      wacc = fmaf(wd[4 * ii + 0], cv.x, wacc);
      wacc = fmaf(wd[4 * ii + 1], cv.y, wacc);
      wacc = fmaf(wd[4 * ii + 2], cv.z, wacc);
      wacc = fmaf(wd[4 * ii + 3], cv.w, wacc);
    }
    g_lds[k][u]   = 1.0f / (1.0f + __expf(-(acc + gxv)));
    wdp_lds[k][u] = wacc;
    __syncthreads();                                   // B1
    if (k == 0) {
      // epilogue + publish (wave 0 only; wave-uniform branch)
      const float wsum = wdp_lds[0][u] + wdp_lds[1][u] + wdp_lds[2][u] + wdp_lds[3][u];
      const float c_st = tanhf(wsum + bdv);
      const float T = T_pre[s];
      const float c_adj = c_all[j] + (T - 1.0f) * c_st;
      const float iv = g_lds[0][u], fv = g_lds[1][u], ov = g_lds[2][u], cgv = g_lds[3][u];
      const float ct = fv * c_adj + iv * cgv;
      const float hn = ov * tanhf(ct);
      c_all[j] = ct;
      h_all[j] = hn;
      float* chunk = bufs + (size_t)(((dir * 4 + wg) * 2) + (s & 1)) * 128;
      __hip_atomic_store(chunk + u,      hn, __ATOMIC_RELAXED, __HIP_MEMORY_SCOPE_AGENT);
      __hip_atomic_store(chunk + 64 + u, ct, __ATOMIC_RELAXED, __HIP_MEMORY_SCOPE_AGENT);
      __builtin_amdgcn_s_waitcnt(0);                   // chunk stores at coherence point
      if (u == 0)
        __hip_atomic_store(myflag, s + 1, __ATOMIC_RELAXED, __HIP_MEMORY_SCOPE_AGENT);
    } else {
      // waves 1..3: poll own sibling's flag (64 lanes, same addr -> 1 request), stage chunk
      while (__hip_atomic_load(sibflag, __ATOMIC_RELAXED, __HIP_MEMORY_SCOPE_AGENT) < s + 1) {
        __builtin_amdgcn_s_sleep(1);
      }
      asm volatile("" ::: "memory");
      const float* chunk = bufs + (size_t)(((dir * 4 + sib) * 2) + (s & 1)) * 128;
      const float hv = __hip_atomic_load(chunk + u,      __ATOMIC_RELAXED, __HIP_MEMORY_SCOPE_AGENT);
      const float cv = __hip_atomic_load(chunk + 64 + u, __ATOMIC_RELAXED, __HIP_MEMORY_SCOPE_AGENT);
      h_all[sib * 64 + u] = hv;
      c_all[sib * 64 + u] = cv;
    }
    __syncthreads();                                   // B2
  }
  if (k == 0) hfin[dir * HHD + c0 + u] = h_all[c0 + u];
}

// ---------------- Kernel D: logits = concat(hf,hb) @ W_cls + b_cls -> sigmoid -> out
__global__ __launch_bounds__(512) void kD(const float* __restrict__ hfin,
                                          const float* __restrict__ Wcls,
                                          const float* __restrict__ bcls,
                                          float* __restrict__ out) {
  __shared__ float red[8];
  const int t = threadIdx.x;          // 0..511
  float v = hfin[t] * Wcls[t];
#pragma unroll
  for (int o = 32; o >= 1; o >>= 1) v += __shfl_down(v, o, 64);
  if ((t & 63) == 0) red[t >> 6] = v;
  __syncthreads();
  if (t == 0) {
    float l = red[0] + red[1] + red[2] + red[3] + red[4] + red[5] + red[6] + red[7] + bcls[0];
    if (isnan(l) || isinf(l)) l = 0.0f;
    float p = 1.0f / (1.0f + expf(-l));
    if (isnan(p) || isinf(p)) p = 0.0f;
    out[0] = p;
  }
}

extern "C" void kernel_launch(void* const* d_in, const int* in_sizes, int n_in,
                              void* d_out, int out_size, void* d_ws, size_t ws_size,
                              hipStream_t stream) {
  const float* inputs    = (const float*)d_in[0];
  const float* times     = (const float*)d_in[1];
  const int*   nid       = (const int*)d_in[2];
  const int*   cid       = (const int*)d_in[3];
  const float* note_emb  = (const float*)d_in[4];
  const float* chunk_emb = (const float*)d_in[5];
  const float* W_comb    = (const float*)d_in[6];
  const float* b_comb    = (const float*)d_in[7];
  const float* ln_g      = (const float*)d_in[8];
  const float* ln_b      = (const float*)d_in[9];
  const float* Wx        = (const float*)d_in[10];
  const float* Wh        = (const float*)d_in[11];
  const float* bg        = (const float*)d_in[12];
  const float* Wd        = (const float*)d_in[13];
  const float* bd        = (const float*)d_in[14];
  const float* W_cls     = (const float*)d_in[15];
  const float* b_cls     = (const float*)d_in[16];

  float* ws   = (float*)d_ws;
  float* xln  = ws;                              // 4096*512    floats
  float* gx   = ws + (size_t)SQ * HD;            // 2*4096*1024 floats
  float* hfin = gx + (size_t)2 * SQ * 1024;      // 512 floats
  float* comm = hfin + 512;                      // flags (8*32 ints) + chunks (8*2*128 floats)

  kA<<<SQ / TS, 512, 0, stream>>>(inputs, nid, cid, note_emb, chunk_emb, W_comb, b_comb, xln);
  kB<<<SQ, 256, 0, stream>>>(xln, ln_g, ln_b);
  kC<<<dim3(SQ / TS, 2), 512, 0, stream>>>(xln, Wx, bg, gx);
  kR<<<8, 256, 0, stream>>>(gx, Wh, Wd, bd, times, comm, hfin);
  kD<<<1, 512, 0, stream>>>(hfin, W_cls, b_cls, (float*)d_out);
}